// Round 9
// baseline (302.762 us; speedup 1.0000x reference)
//
#include <hip/hip_runtime.h>
#include <hip/hip_bf16.h>

typedef unsigned short ushort_t;
typedef unsigned int uint_t;
typedef __attribute__((ext_vector_type(8))) short bf16x8;
typedef __attribute__((ext_vector_type(4))) float f32x4;

#define MFMA32(a, b, c) __builtin_amdgcn_mfma_f32_16x16x32_bf16(a, b, c, 0, 0, 0)

static constexpr int BATCH = 16;
static constexpr int SEQ   = 4096;   // H*W
static constexpr int CH    = 128;
static constexpr int NGRP  = 32;
static constexpr float EPS = 1e-6f;
// softmax scale folded into exp2 domain AND pre-folded into Q projection:
static constexpr float C2 = 0.08838834764831845f * 1.4426950408889634f;

__device__ inline ushort_t f2bf(float f) {
    uint_t u = __float_as_uint(f);
    u = (u + 0x7fff + ((u >> 16) & 1)) >> 16;
    return (ushort_t)u;
}

// bare v_exp_f32 via the clang intrinsic (schedulable, promotable — no inline
// asm).  Args bounded |x|<~35 in this kernel -> in-range, matches exp2f.
// (r16/r17/r18 A-B: inline-asm variants and s_setprio both induce ~17MB of
// scheduling spill traffic; this intrinsic alone is clean: 168.8->139.6us.)
__device__ inline float exp2_fast(float x) {
    return __builtin_amdgcn_exp2f(x);
}

// ---------------- fused GN-partial + weight prep (one launch) ----------------
// blocks 0..255: GroupNorm partial sums, NON-ATOMIC into private per-chunk
// slots stats[b][chunk][g][2] (removes hipMemsetAsync + atomic round-trips;
// gemm_qkv finalizes by summing the 16 chunk slots).
// blocks 256..259: W fp32 [k][n] -> Wt bf16 [n][k] (L2-resident for the
// whole pipeline; every GEMM wave loads B-fragments straight from L2).
__global__ __launch_bounds__(256) void gn_wprep(const float* __restrict__ x,
                                                float* __restrict__ stats,
                                                const float* __restrict__ W0,
                                                const float* __restrict__ W1,
                                                const float* __restrict__ W2,
                                                const float* __restrict__ W3,
                                                ushort_t* __restrict__ wt) {
    int bid = blockIdx.x;
    int t = threadIdx.x;
    if (bid >= 256) {
        // ---- weight prep ----
        int m = bid - 256;
        const float* Ws[4] = {W0, W1, W2, W3};
        const float* W = Ws[m];
        ushort_t* out = wt + (size_t)m * CH * CH;
        __shared__ ushort_t tile[128][130];
        for (int i = 0; i < 16; ++i) {
            int idx = (t + i * 256) * 4;
            int kk = idx >> 7, n = idx & 127;
            float4 w4 = *(const float4*)(W + (size_t)kk * CH + n);
            tile[n + 0][kk] = f2bf(w4.x);
            tile[n + 1][kk] = f2bf(w4.y);
            tile[n + 2][kk] = f2bf(w4.z);
            tile[n + 3][kk] = f2bf(w4.w);
        }
        __syncthreads();
        for (int i = 0; i < 8; ++i) {
            int idx = (t + i * 256) * 8;
            int n = idx >> 7, kk = idx & 127;
            ushort_t tmp[8];
            for (int u = 0; u < 8; ++u) tmp[u] = tile[n][kk + u];
            *(uint4*)&out[(size_t)n * CH + kk] = *(const uint4*)tmp;
        }
        return;
    }
    // ---- GN partial sums ----
    int b = bid >> 4, chunk = bid & 15;
    int c4 = (t & 31) * 4;   // one group = 4 channels
    int rowoff = t >> 5;     // 0..7
    const float* xb = x + (size_t)b * SEQ * CH;
    float s1 = 0.f, s2 = 0.f;
    int base_row = chunk * 256;
    for (int i = 0; i < 32; ++i) {
        int r = base_row + i * 8 + rowoff;
        float4 v = *(const float4*)(xb + (size_t)r * CH + c4);
        s1 += v.x + v.y + v.z + v.w;
        s2 += v.x * v.x + v.y * v.y + v.z * v.z + v.w * v.w;
    }
    __shared__ float red[256][2];
    red[t][0] = s1; red[t][1] = s2;
    __syncthreads();
    if (t < 32) {
        float a1 = 0.f, a2 = 0.f;
        for (int ro = 0; ro < 8; ++ro) {
            a1 += red[ro * 32 + t][0];
            a2 += red[ro * 32 + t][1];
        }
        float* slot = stats + ((size_t)(b * 16 + chunk) * 32 + t) * 2;
        slot[0] = a1;
        slot[1] = a2;
    }
}

// ---------------- fused normalize + QKV GEMM (512 threads, 8 waves) ----------
// r20: 8 waves x 16 rows each (was 4 x 32) — same grid/LDS, 16 waves/CU for
// latency hiding of the L2 B-fragment loads (~200cyc each on the dep chain).
// B-fragments direct from precomputed Wt (L2-resident).  2 barriers total.
// q pre-scaled by C2; v written TRANSPOSED vt[b][d][seq], packed uint2 stores.
__global__ __launch_bounds__(512) void gemm_qkv(const float* __restrict__ x,
                                                const float* __restrict__ stats,
                                                const float* __restrict__ gsc,
                                                const float* __restrict__ gbi,
                                                const ushort_t* __restrict__ wt,
                                                const float* __restrict__ Bq,
                                                const float* __restrict__ Bk,
                                                const float* __restrict__ Bv,
                                                ushort_t* __restrict__ outq,
                                                ushort_t* __restrict__ outk,
                                                ushort_t* __restrict__ outvt) {
    __shared__ ushort_t lds_a[128][136];  // full 128x128 normalized A tile (bf16)
    __shared__ float2 gstat[32];
    int t = threadIdx.x;
    int wv = t >> 6, lane = t & 63, quad = lane >> 4, l16 = lane & 15;
    size_t m0 = (size_t)blockIdx.x * 128;
    int batch = (int)(m0 >> 12);
    int seq0  = (int)(m0 & 4095);
    // gn_finalize: sum the 16 per-chunk raw slots for this batch
    if (t < 32) {
        float sum = 0.f, sq = 0.f;
        for (int c = 0; c < 16; ++c) {
            const float* slot = stats + ((size_t)(batch * 16 + c) * 32 + t) * 2;
            sum += slot[0];
            sq  += slot[1];
        }
        float mean = sum / 16384.f;
        float var  = sq / 16384.f - mean * mean;
        gstat[t] = float2{mean, __frsqrt_rn(var + EPS)};
    }
    __syncthreads();
    // stage A once, normalizing x -> h in flight (512 threads, 4 rounds)
    for (int i = 0; i < 4; ++i) {
        int idx = (t + i * 512) * 8;
        int r = idx >> 7, c = idx & 127;
        size_t row = m0 + r;
        float4 xa = *(const float4*)(x + row * CH + c);
        float4 xc = *(const float4*)(x + row * CH + c + 4);
        float2 stA = gstat[c >> 2];
        float2 stB = gstat[(c >> 2) + 1];
        float4 sA = *(const float4*)(gsc + c), sB = *(const float4*)(gsc + c + 4);
        float4 bA = *(const float4*)(gbi + c), bB = *(const float4*)(gbi + c + 4);
        ushort_t tmp[8];
        tmp[0] = f2bf((xa.x - stA.x) * stA.y * sA.x + bA.x);
        tmp[1] = f2bf((xa.y - stA.x) * stA.y * sA.y + bA.y);
        tmp[2] = f2bf((xa.z - stA.x) * stA.y * sA.z + bA.z);
        tmp[3] = f2bf((xa.w - stA.x) * stA.y * sA.w + bA.w);
        tmp[4] = f2bf((xc.x - stB.x) * stB.y * sB.x + bB.x);
        tmp[5] = f2bf((xc.y - stB.x) * stB.y * sB.y + bB.y);
        tmp[6] = f2bf((xc.z - stB.x) * stB.y * sB.z + bB.z);
        tmp[7] = f2bf((xc.w - stB.x) * stB.y * sB.w + bB.w);
        *(uint4*)&lds_a[r][c] = *(const uint4*)tmp;
    }
    __syncthreads();   // A tile ready; no further barriers
    for (int j = 0; j < 3; ++j) {
        const ushort_t* wtj = wt + (size_t)j * CH * CH;   // Wt[n][k] bf16
        const float* Bi = (j == 0) ? Bq : (j == 1) ? Bk : Bv;
        f32x4 acc[8] = {};
        for (int kh = 0; kh < 2; ++kh) {
            int k0 = kh * 64;
            for (int ks = 0; ks < 2; ++ks) {
                bf16x8 afrag = *(const bf16x8*)&lds_a[wv * 16 + l16][k0 + ks * 32 + quad * 8];
                for (int tc = 0; tc < 8; ++tc) {
                    bf16x8 bfrag = *(const bf16x8*)(wtj + (size_t)(tc * 16 + l16) * CH + k0 + ks * 32 + quad * 8);
                    acc[tc] = MFMA32(afrag, bfrag, acc[tc]);
                }
            }
        }
        // epilogue: wave wv owns rows wv*16 .. wv*16+15
        int rl = wv * 16 + quad * 4;
        for (int tc = 0; tc < 8; ++tc) {
            int col = tc * 16 + l16;
            float bval = Bi[col];
            if (j == 2) {
                // V^T: rows rl..rl+3 are consecutive seq positions of col
                ushort_t tmp[4];
                for (int r = 0; r < 4; ++r) tmp[r] = f2bf(acc[tc][r] + bval);
                *(uint2*)&outvt[(size_t)batch * CH * SEQ + (size_t)col * SEQ + seq0 + rl] =
                    *(const uint2*)tmp;
            } else {
                ushort_t* op = (j == 0) ? outq : outk;
                for (int r = 0; r < 4; ++r) {
                    float vv = acc[tc][r] + bval;
                    if (j == 0) vv *= C2;   // fold softmax scale into q
                    op[(m0 + rl + r) * CH + col] = f2bf(vv);
                }
            }
        }
    }
}

// ---------------- flash attention r18 (UNCHANGED — 139.6us verified) ---------
// Cross-iteration pipeline (QK_{i+1} fused with PV_i), unnormalized exp2
// softmax via __builtin_amdgcn_exp2f, dbuf, 1 barrier/iter, NO setprio.
__global__ __launch_bounds__(256, 2) void flash_attn18(const ushort_t* __restrict__ q,
                                                       const ushort_t* __restrict__ k,
                                                       const ushort_t* __restrict__ vt,
                                                       ushort_t* __restrict__ o) {
    int bid = blockIdx.x;
    int b = bid & 15, qt = bid >> 4;
    int t = threadIdx.x;
    int wv = t >> 6, lane = t & 63, quad = lane >> 4, l16 = lane & 15;
    const size_t SB = (size_t)SEQ * CH;
    const ushort_t* qb  = q  + (size_t)b * SB;
    const ushort_t* kb  = k  + (size_t)b * SB;
    const ushort_t* vtb = vt + (size_t)b * SB;   // [d][seq]

    __shared__ ushort_t lds_k[2][64][136];    // [buf][key][d]
    __shared__ ushort_t lds_vt[2][128][72];   // [buf][d][key_local PERMUTED]

    int qrow_base = qt * 128 + wv * 32;       // 4 waves x 32 q-rows
    bf16x8 qfrag[2][4];
#pragma unroll
    for (int nt = 0; nt < 2; ++nt)
#pragma unroll
        for (int ks = 0; ks < 4; ++ks)
            qfrag[nt][ks] = *(const bf16x8*)(qb + (size_t)(qrow_base + nt * 16 + l16) * CH + ks * 32 + quad * 8);

    f32x4 oacc[8][2] = {};        // [mt=d/16][nt]
    float psum[2] = {0.f, 0.f};   // per-lane partial row-sums (reduced at end)

    int kr_row  = t >> 4;          // 0..15 (+16i)
    int kr_col  = (t & 15) * 8;
    int vr_d    = t >> 3;          // 0..31 (+32i)
    int vr_beta = t & 7;
    int vc0 = 32 * (vr_beta >> 2) + 16 * (vr_beta & 1) + 4 * ((vr_beta >> 1) & 1);

    const ushort_t* kp = kb + (size_t)kr_row * CH + kr_col;
    const ushort_t* vp = vtb + (size_t)vr_d * SEQ + vr_beta * 8;

    uint4 kr[4], vr[4], k1[4];
#pragma unroll
    for (int i = 0; i < 4; ++i) kr[i] = *(const uint4*)(kp + (size_t)i * 16 * CH);
#pragma unroll
    for (int i = 0; i < 4; ++i) vr[i] = *(const uint4*)(vp + (size_t)i * 32 * SEQ);
#pragma unroll
    for (int i = 0; i < 4; ++i) k1[i] = *(const uint4*)(kp + (size_t)(64 + i * 16) * CH);
    kp += 2 * 64 * CH;   // -> tile 2
    vp += 64;            // -> tile 1
#pragma unroll
    for (int i = 0; i < 4; ++i) {
        *(uint4*)&lds_k[0][kr_row + 16 * i][kr_col] = kr[i];
        *(uint4*)&lds_k[1][kr_row + 16 * i][kr_col] = k1[i];
        *(uint2*)&lds_vt[0][vr_d + 32 * i][vc0]     = uint2{vr[i].x, vr[i].y};
        *(uint2*)&lds_vt[0][vr_d + 32 * i][vc0 + 8] = uint2{vr[i].z, vr[i].w};
    }
    __syncthreads();

    // prologue compute: QK_0 -> pkp_0 (unnormalized exp2)
    bf16x8 pkp[2][2];   // [nt][half], live across iterations
    {
        f32x4 s[4][2] = {};
#pragma unroll
        for (int ks = 0; ks < 4; ++ks) {
            bf16x8 kf[4];
#pragma unroll
            for (int kt = 0; kt < 4; ++kt)
                kf[kt] = *(const bf16x8*)&lds_k[0][kt * 16 + l16][ks * 32 + quad * 8];
#pragma unroll
            for (int kt = 0; kt < 4; ++kt) {
                s[kt][0] = MFMA32(kf[kt], qfrag[0][ks], s[kt][0]);
                s[kt][1] = MFMA32(kf[kt], qfrag[1][ks], s[kt][1]);
            }
        }
#pragma unroll
        for (int nt = 0; nt < 2; ++nt) {
            float ps = 0.f;
            uint_t pb[8];
#pragma unroll
            for (int kt = 0; kt < 4; ++kt) {
                float p0 = exp2_fast(s[kt][nt][0]);
                float p1 = exp2_fast(s[kt][nt][1]);
                float p2 = exp2_fast(s[kt][nt][2]);
                float p3 = exp2_fast(s[kt][nt][3]);
                ps += (p0 + p1) + (p2 + p3);
                __hip_bfloat162 h01 = __float22bfloat162_rn(float2{p0, p1});
                __hip_bfloat162 h23 = __float22bfloat162_rn(float2{p2, p3});
                __builtin_memcpy(&pb[kt * 2 + 0], &h01, 4);
                __builtin_memcpy(&pb[kt * 2 + 1], &h23, 4);
            }
            psum[nt] += ps;
            __builtin_memcpy(&pkp[nt][0], &pb[0], 16);
            __builtin_memcpy(&pkp[nt][1], &pb[4], 16);
        }
    }
    __syncthreads();   // all waves done reading lds_k[0] before iter0 overwrites it

    // main loop: iter it computes PV(tile it) + QK(tile it+1)
    for (int it = 0; it < 63; ++it) {
        int knxt = (it + 1) & 1;   // K_{it+1} read buffer; also V_{it+1} write buffer
        int vcur = it & 1;         // V_it read buffer;    also K_{it+2} write buffer
#pragma unroll
        for (int i = 0; i < 4; ++i) kr[i] = *(const uint4*)(kp + (size_t)i * 16 * CH);
#pragma unroll
        for (int i = 0; i < 4; ++i) vr[i] = *(const uint4*)(vp + (size_t)i * 32 * SEQ);
        kp += 64 * CH; vp += 64;

        // fused MFMA block: QK_{it+1} interleaved with PV_it
        f32x4 s[4][2] = {};
#pragma unroll
        for (int u = 0; u < 4; ++u) {
            bf16x8 kf[4];
#pragma unroll
            for (int kt = 0; kt < 4; ++kt)
                kf[kt] = *(const bf16x8*)&lds_k[knxt][kt * 16 + l16][u * 32 + quad * 8];
#pragma unroll
            for (int kt = 0; kt < 4; ++kt) {
                s[kt][0] = MFMA32(kf[kt], qfrag[0][u], s[kt][0]);
                s[kt][1] = MFMA32(kf[kt], qfrag[1][u], s[kt][1]);
            }
#pragma unroll
            for (int m2 = 0; m2 < 2; ++m2) {
                int mt = u * 2 + m2;
                bf16x8 vf0 = *(const bf16x8*)&lds_vt[vcur][mt * 16 + l16][quad * 8];
                bf16x8 vf1 = *(const bf16x8*)&lds_vt[vcur][mt * 16 + l16][32 + quad * 8];
                oacc[mt][0] = MFMA32(vf0, pkp[0][0], oacc[mt][0]);
                oacc[mt][0] = MFMA32(vf1, pkp[0][1], oacc[mt][0]);
                oacc[mt][1] = MFMA32(vf0, pkp[1][0], oacc[mt][1]);
                oacc[mt][1] = MFMA32(vf1, pkp[1][1], oacc[mt][1]);
            }
        }

        // softmax(tile it+1) -> pkp for next iteration (overlaps store tail)
#pragma unroll
        for (int nt = 0; nt < 2; ++nt) {
            float ps = 0.f;
            uint_t pb[8];
#pragma unroll
            for (int kt = 0; kt < 4; ++kt) {
                float p0 = exp2_fast(s[kt][nt][0]);
                float p1 = exp2_fast(s[kt][nt][1]);
                float p2 = exp2_fast(s[kt][nt][2]);
                float p3 = exp2_fast(s[kt][nt][3]);
                ps += (p0 + p1) + (p2 + p3);
                __hip_bfloat162 h01 = __float22bfloat162_rn(float2{p0, p1});
                __hip_bfloat162 h23 = __float22bfloat162_rn(float2{p2, p3});
                __builtin_memcpy(&pb[kt * 2 + 0], &h01, 4);
                __builtin_memcpy(&pb[kt * 2 + 1], &h23, 4);
            }
            psum[nt] += ps;
            __builtin_memcpy(&pkp[nt][0], &pb[0], 16);
            __builtin_memcpy(&pkp[nt][1], &pb[4], 16);
        }

        // stage writes: K_{it+2} -> lds_k[vcur], V_{it+1} -> lds_vt[knxt]
#pragma unroll
        for (int i = 0; i < 4; ++i) {
            *(uint4*)&lds_k[vcur][kr_row + 16 * i][kr_col] = kr[i];
            *(uint2*)&lds_vt[knxt][vr_d + 32 * i][vc0]     = uint2{vr[i].x, vr[i].y};
            *(uint2*)&lds_vt[knxt][vr_d + 32 * i][vc0 + 8] = uint2{vr[i].z, vr[i].w};
        }
        __syncthreads();   // single barrier per iteration
    }

    // epilogue: PV for tile 63 (lds_vt[1], pkp_63 computed at it=62)
#pragma unroll
    for (int mt = 0; mt < 8; ++mt) {
        bf16x8 vf0 = *(const bf16x8*)&lds_vt[1][mt * 16 + l16][quad * 8];
        bf16x8 vf1 = *(const bf16x8*)&lds_vt[1][mt * 16 + l16][32 + quad * 8];
        oacc[mt][0] = MFMA32(vf0, pkp[0][0], oacc[mt][0]);
        oacc[mt][0] = MFMA32(vf1, pkp[0][1], oacc[mt][0]);
        oacc[mt][1] = MFMA32(vf0, pkp[1][0], oacc[mt][1]);
        oacc[mt][1] = MFMA32(vf1, pkp[1][1], oacc[mt][1]);
    }

    // epilogue: cross-lane row-sum reduce (ONCE), then O[qrow][d] = O^T / l
#pragma unroll
    for (int nt = 0; nt < 2; ++nt) {
        float tot = psum[nt];
        tot += __shfl_xor(tot, 16, 64);
        tot += __shfl_xor(tot, 32, 64);
        float inv = 1.f / tot;
        size_t row = (size_t)b * SEQ + qrow_base + nt * 16 + l16;
#pragma unroll
        for (int mt = 0; mt < 8; ++mt) {
            ushort_t tmp[4];
#pragma unroll
            for (int r = 0; r < 4; ++r) tmp[r] = f2bf(oacc[mt][nt][r] * inv);
            *(uint2*)&o[row * CH + mt * 16 + quad * 4] = *(const uint2*)tmp;
        }
    }
}

// ---------------- final GEMM (512 threads, 8 waves): A@Wo + bias + resid -----
__global__ __launch_bounds__(512) void gemm_out(const ushort_t* __restrict__ A,
                                                const ushort_t* __restrict__ wto,
                                                const float* __restrict__ bias,
                                                const float* __restrict__ resid,
                                                float* __restrict__ out) {
    __shared__ ushort_t lds_a[128][136];
    int t = threadIdx.x;
    int wv = t >> 6, lane = t & 63, quad = lane >> 4, l16 = lane & 15;
    size_t m0 = (size_t)blockIdx.x * 128;
    // stage full A tile (bf16, vector copy, 512 threads x 4 rounds)
    for (int i = 0; i < 4; ++i) {
        int idx = (t + i * 512) * 8;
        int r = idx >> 7, c = idx & 127;
        *(uint4*)&lds_a[r][c] = *(const uint4*)(A + (m0 + r) * CH + c);
    }
    __syncthreads();
    f32x4 acc[8] = {};
    for (int kh = 0; kh < 2; ++kh) {
        int k0 = kh * 64;
        for (int ks = 0; ks < 2; ++ks) {
            bf16x8 afrag = *(const bf16x8*)&lds_a[wv * 16 + l16][k0 + ks * 32 + quad * 8];
            for (int tc = 0; tc < 8; ++tc) {
                bf16x8 bfrag = *(const bf16x8*)(wto + (size_t)(tc * 16 + l16) * CH + k0 + ks * 32 + quad * 8);
                acc[tc] = MFMA32(afrag, bfrag, acc[tc]);
            }
        }
    }
    int rl = wv * 16 + quad * 4;
    for (int tc = 0; tc < 8; ++tc) {
        int col = tc * 16 + l16;
        float bval = bias[col];
        for (int r = 0; r < 4; ++r) {
            size_t row = m0 + rl + r;
            out[row * CH + col] = acc[tc][r] + bval + resid[row * CH + col];
        }
    }
}

extern "C" void kernel_launch(void* const* d_in, const int* in_sizes, int n_in,
                              void* d_out, int out_size, void* d_ws, size_t ws_size,
                              hipStream_t stream) {
    const float* x   = (const float*)d_in[0];
    const float* gsc = (const float*)d_in[1];
    const float* gbi = (const float*)d_in[2];
    const float* wq  = (const float*)d_in[3];
    const float* bq  = (const float*)d_in[4];
    const float* wk  = (const float*)d_in[5];
    const float* bk  = (const float*)d_in[6];
    const float* wvp = (const float*)d_in[7];
    const float* bv  = (const float*)d_in[8];
    const float* wo  = (const float*)d_in[9];
    const float* bo  = (const float*)d_in[10];
    float* outp = (float*)d_out;

    const size_t NELEM = (size_t)BATCH * SEQ * CH;  // 8388608
    ushort_t* qbuf  = (ushort_t*)d_ws;
    ushort_t* kbuf  = qbuf + NELEM;
    ushort_t* vtbuf = kbuf + NELEM;
    ushort_t* abuf  = vtbuf + NELEM;   // attention output
    ushort_t* wtbuf = abuf + NELEM;    // 4 x 128x128 bf16 W^T (128 KB)
    float*    stats = (float*)(wtbuf + 4 * CH * CH);  // 16x16x32x2 raw sums (64 KB)
    // note: flash_attn18 prefetches one K tile past the K buffer end (reads
    // land in vtbuf) and one V tile past vtbuf (lands in abuf); values unused
    // — keep buffer order qbuf,kbuf,vtbuf,abuf.

    gn_wprep<<<260, 256, 0, stream>>>(x, stats, wq, wk, wvp, wo, wtbuf);
    gemm_qkv<<<512, 512, 0, stream>>>(x, stats, gsc, gbi, wtbuf, bq, bk, bv,
                                      qbuf, kbuf, vtbuf);
    flash_attn18<<<512, 256, 0, stream>>>(qbuf, kbuf, vtbuf, abuf);
    gemm_out<<<512, 512, 0, stream>>>(abuf, wtbuf + 3 * CH * CH, bo, x, outp);
}

// Round 10
// 278.453 us; speedup vs baseline: 1.0873x; 1.0873x over previous
//
#include <hip/hip_runtime.h>
#include <hip/hip_bf16.h>

typedef unsigned short ushort_t;
typedef unsigned int uint_t;
typedef __attribute__((ext_vector_type(8))) short bf16x8;
typedef __attribute__((ext_vector_type(4))) float f32x4;

#define MFMA32(a, b, c) __builtin_amdgcn_mfma_f32_16x16x32_bf16(a, b, c, 0, 0, 0)

static constexpr int BATCH = 16;
static constexpr int SEQ   = 4096;   // H*W
static constexpr int CH    = 128;
static constexpr int NGRP  = 32;
static constexpr float EPS = 1e-6f;
// softmax scale folded into exp2 domain AND pre-folded into Q projection:
static constexpr float C2 = 0.08838834764831845f * 1.4426950408889634f;

__device__ inline ushort_t f2bf(float f) {
    uint_t u = __float_as_uint(f);
    u = (u + 0x7fff + ((u >> 16) & 1)) >> 16;
    return (ushort_t)u;
}

// bare v_exp_f32 via the clang intrinsic (schedulable, promotable — no inline
// asm).  Args bounded |x|<~35 in this kernel -> in-range, matches exp2f.
// (r16/r17/r18 A-B: inline-asm variants and s_setprio both induce ~17MB of
// scheduling spill traffic; this intrinsic alone is clean: 168.8->139.6us.)
__device__ inline float exp2_fast(float x) {
    return __builtin_amdgcn_exp2f(x);
}

// ---------------- fused GN-partial + weight prep (one launch) ----------------
// blocks 0..255: GroupNorm partial sums, NON-ATOMIC into private per-chunk
// slots stats[b][chunk][g][2]; gemm_qkv finalizes by summing the 16 slots.
// blocks 256..259: W fp32 [k][n] -> Wt bf16 [n][k] (L2-resident afterwards).
__global__ __launch_bounds__(256) void gn_wprep(const float* __restrict__ x,
                                                float* __restrict__ stats,
                                                const float* __restrict__ W0,
                                                const float* __restrict__ W1,
                                                const float* __restrict__ W2,
                                                const float* __restrict__ W3,
                                                ushort_t* __restrict__ wt) {
    int bid = blockIdx.x;
    int t = threadIdx.x;
    if (bid >= 256) {
        // ---- weight prep ----
        int m = bid - 256;
        const float* Ws[4] = {W0, W1, W2, W3};
        const float* W = Ws[m];
        ushort_t* out = wt + (size_t)m * CH * CH;
        __shared__ ushort_t tile[128][130];
        for (int i = 0; i < 16; ++i) {
            int idx = (t + i * 256) * 4;
            int kk = idx >> 7, n = idx & 127;
            float4 w4 = *(const float4*)(W + (size_t)kk * CH + n);
            tile[n + 0][kk] = f2bf(w4.x);
            tile[n + 1][kk] = f2bf(w4.y);
            tile[n + 2][kk] = f2bf(w4.z);
            tile[n + 3][kk] = f2bf(w4.w);
        }
        __syncthreads();
        for (int i = 0; i < 8; ++i) {
            int idx = (t + i * 256) * 8;
            int n = idx >> 7, kk = idx & 127;
            ushort_t tmp[8];
            for (int u = 0; u < 8; ++u) tmp[u] = tile[n][kk + u];
            *(uint4*)&out[(size_t)n * CH + kk] = *(const uint4*)tmp;
        }
        return;
    }
    // ---- GN partial sums ----
    int b = bid >> 4, chunk = bid & 15;
    int c4 = (t & 31) * 4;   // one group = 4 channels
    int rowoff = t >> 5;     // 0..7
    const float* xb = x + (size_t)b * SEQ * CH;
    float s1 = 0.f, s2 = 0.f;
    int base_row = chunk * 256;
    for (int i = 0; i < 32; ++i) {
        int r = base_row + i * 8 + rowoff;
        float4 v = *(const float4*)(xb + (size_t)r * CH + c4);
        s1 += v.x + v.y + v.z + v.w;
        s2 += v.x * v.x + v.y * v.y + v.z * v.z + v.w * v.w;
    }
    __shared__ float red[256][2];
    red[t][0] = s1; red[t][1] = s2;
    __syncthreads();
    if (t < 32) {
        float a1 = 0.f, a2 = 0.f;
        for (int ro = 0; ro < 8; ++ro) {
            a1 += red[ro * 32 + t][0];
            a2 += red[ro * 32 + t][1];
        }
        float* slot = stats + ((size_t)(b * 16 + chunk) * 32 + t) * 2;
        slot[0] = a1;
        slot[1] = a2;
    }
}

// ---------------- fused normalize + QKV GEMM (r19 256-thread shape) ----------
// r20 post-mortem: 512-thread/16-row-per-wave variant doubled per-block L2
// B-loads and regressed — reverted to the r19-proven 4-wave x 32-row shape.
// B-fragments direct from precomputed Wt (L2-resident).  2 barriers total.
__global__ __launch_bounds__(256) void gemm_qkv(const float* __restrict__ x,
                                                const float* __restrict__ stats,
                                                const float* __restrict__ gsc,
                                                const float* __restrict__ gbi,
                                                const ushort_t* __restrict__ wt,
                                                const float* __restrict__ Bq,
                                                const float* __restrict__ Bk,
                                                const float* __restrict__ Bv,
                                                ushort_t* __restrict__ outq,
                                                ushort_t* __restrict__ outk,
                                                ushort_t* __restrict__ outvt) {
    __shared__ ushort_t lds_a[128][136];  // full 128x128 normalized A tile (bf16)
    __shared__ float2 gstat[32];
    int t = threadIdx.x;
    int wv = t >> 6, lane = t & 63, quad = lane >> 4, l16 = lane & 15;
    size_t m0 = (size_t)blockIdx.x * 128;
    int batch = (int)(m0 >> 12);
    int seq0  = (int)(m0 & 4095);
    // gn_finalize: sum the 16 per-chunk raw slots for this batch
    if (t < 32) {
        float sum = 0.f, sq = 0.f;
        for (int c = 0; c < 16; ++c) {
            const float* slot = stats + ((size_t)(batch * 16 + c) * 32 + t) * 2;
            sum += slot[0];
            sq  += slot[1];
        }
        float mean = sum / 16384.f;
        float var  = sq / 16384.f - mean * mean;
        gstat[t] = float2{mean, __frsqrt_rn(var + EPS)};
    }
    __syncthreads();
    // stage A once, normalizing x -> h in flight
    for (int i = 0; i < 8; ++i) {
        int idx = (t + i * 256) * 8;
        int r = idx >> 7, c = idx & 127;
        size_t row = m0 + r;
        float4 xa = *(const float4*)(x + row * CH + c);
        float4 xc = *(const float4*)(x + row * CH + c + 4);
        float2 stA = gstat[c >> 2];
        float2 stB = gstat[(c >> 2) + 1];
        float4 sA = *(const float4*)(gsc + c), sB = *(const float4*)(gsc + c + 4);
        float4 bA = *(const float4*)(gbi + c), bB = *(const float4*)(gbi + c + 4);
        ushort_t tmp[8];
        tmp[0] = f2bf((xa.x - stA.x) * stA.y * sA.x + bA.x);
        tmp[1] = f2bf((xa.y - stA.x) * stA.y * sA.y + bA.y);
        tmp[2] = f2bf((xa.z - stA.x) * stA.y * sA.z + bA.z);
        tmp[3] = f2bf((xa.w - stA.x) * stA.y * sA.w + bA.w);
        tmp[4] = f2bf((xc.x - stB.x) * stB.y * sB.x + bB.x);
        tmp[5] = f2bf((xc.y - stB.x) * stB.y * sB.y + bB.y);
        tmp[6] = f2bf((xc.z - stB.x) * stB.y * sB.z + bB.z);
        tmp[7] = f2bf((xc.w - stB.x) * stB.y * sB.w + bB.w);
        *(uint4*)&lds_a[r][c] = *(const uint4*)tmp;
    }
    __syncthreads();   // A tile ready; no further barriers
    for (int j = 0; j < 3; ++j) {
        const ushort_t* wtj = wt + (size_t)j * CH * CH;   // Wt[n][k] bf16
        const float* Bi = (j == 0) ? Bq : (j == 1) ? Bk : Bv;
        f32x4 acc[2][8] = {};
        for (int kh = 0; kh < 2; ++kh) {
            int k0 = kh * 64;
            for (int ks = 0; ks < 2; ++ks) {
                bf16x8 afrag[2];
                for (int tr = 0; tr < 2; ++tr)
                    afrag[tr] = *(const bf16x8*)&lds_a[wv * 32 + tr * 16 + l16][k0 + ks * 32 + quad * 8];
                for (int tc = 0; tc < 8; ++tc) {
                    bf16x8 bfrag = *(const bf16x8*)(wtj + (size_t)(tc * 16 + l16) * CH + k0 + ks * 32 + quad * 8);
                    for (int tr = 0; tr < 2; ++tr)
                        acc[tr][tc] = MFMA32(afrag[tr], bfrag, acc[tr][tc]);
                }
            }
        }
        // epilogue
        for (int tc = 0; tc < 8; ++tc) {
            int col = tc * 16 + l16;
            float bval = Bi[col];
            for (int tr = 0; tr < 2; ++tr) {
                int rl = wv * 32 + tr * 16 + quad * 4;
                if (j == 2) {
                    ushort_t tmp[4];
                    for (int r = 0; r < 4; ++r) tmp[r] = f2bf(acc[tr][tc][r] + bval);
                    *(uint2*)&outvt[(size_t)batch * CH * SEQ + (size_t)col * SEQ + seq0 + rl] =
                        *(const uint2*)tmp;
                } else {
                    ushort_t* op = (j == 0) ? outq : outk;
                    for (int r = 0; r < 4; ++r) {
                        float vv = acc[tr][tc][r] + bval;
                        if (j == 0) vv *= C2;   // fold softmax scale into q
                        op[(m0 + rl + r) * CH + col] = f2bf(vv);
                    }
                }
            }
        }
    }
}

// ---------------- flash attention r21: r18 core + FUSED OUTPUT PROJECTION ----
// Each block already holds 128 complete O rows (full d=128) at epilogue time;
// gemm_out only re-read them from HBM to run a 128x128 GEMM.  r21 finishes in
// place: after the last PV, write normalized bf16 O rows into the now-dead
// lds_k space (per-wave private [32][136] slice, exact fit, one barrier),
// read back standard A-fragments (same pattern as gemm_qkv's lds_a — proven
// conflict-clean), multiply by L2-resident Wo^T fragments, add bias+resid,
// store fp32.  Numerics identical to the two-kernel path (same f2bf(oacc*inv)
// round, same MFMA order).  Eliminates: gemm_out launch, 16.7MB abuf write,
// 16.7MB abuf read, its LDS staging + barrier.
__global__ __launch_bounds__(256, 2) void flash_attn21(const ushort_t* __restrict__ q,
                                                       const ushort_t* __restrict__ k,
                                                       const ushort_t* __restrict__ vt,
                                                       const ushort_t* __restrict__ wto,
                                                       const float* __restrict__ Bo,
                                                       const float* __restrict__ xres,
                                                       float* __restrict__ outp) {
    int bid = blockIdx.x;
    int b = bid & 15, qt = bid >> 4;
    int t = threadIdx.x;
    int wv = t >> 6, lane = t & 63, quad = lane >> 4, l16 = lane & 15;
    const size_t SB = (size_t)SEQ * CH;
    const ushort_t* qb  = q  + (size_t)b * SB;
    const ushort_t* kb  = k  + (size_t)b * SB;
    const ushort_t* vtb = vt + (size_t)b * SB;   // [d][seq]

    __shared__ ushort_t lds_k[2][64][136];    // [buf][key][d]; reused as O slices
    __shared__ ushort_t lds_vt[2][128][72];   // [buf][d][key_local PERMUTED]

    int qrow_base = qt * 128 + wv * 32;       // 4 waves x 32 q-rows
    bf16x8 qfrag[2][4];
#pragma unroll
    for (int nt = 0; nt < 2; ++nt)
#pragma unroll
        for (int ks = 0; ks < 4; ++ks)
            qfrag[nt][ks] = *(const bf16x8*)(qb + (size_t)(qrow_base + nt * 16 + l16) * CH + ks * 32 + quad * 8);

    f32x4 oacc[8][2] = {};        // [mt=d/16][nt]
    float psum[2] = {0.f, 0.f};   // per-lane partial row-sums (reduced at end)

    int kr_row  = t >> 4;          // 0..15 (+16i)
    int kr_col  = (t & 15) * 8;
    int vr_d    = t >> 3;          // 0..31 (+32i)
    int vr_beta = t & 7;
    int vc0 = 32 * (vr_beta >> 2) + 16 * (vr_beta & 1) + 4 * ((vr_beta >> 1) & 1);

    const ushort_t* kp = kb + (size_t)kr_row * CH + kr_col;
    const ushort_t* vp = vtb + (size_t)vr_d * SEQ + vr_beta * 8;

    uint4 kr[4], vr[4], k1[4];
#pragma unroll
    for (int i = 0; i < 4; ++i) kr[i] = *(const uint4*)(kp + (size_t)i * 16 * CH);
#pragma unroll
    for (int i = 0; i < 4; ++i) vr[i] = *(const uint4*)(vp + (size_t)i * 32 * SEQ);
#pragma unroll
    for (int i = 0; i < 4; ++i) k1[i] = *(const uint4*)(kp + (size_t)(64 + i * 16) * CH);
    kp += 2 * 64 * CH;   // -> tile 2
    vp += 64;            // -> tile 1
#pragma unroll
    for (int i = 0; i < 4; ++i) {
        *(uint4*)&lds_k[0][kr_row + 16 * i][kr_col] = kr[i];
        *(uint4*)&lds_k[1][kr_row + 16 * i][kr_col] = k1[i];
        *(uint2*)&lds_vt[0][vr_d + 32 * i][vc0]     = uint2{vr[i].x, vr[i].y};
        *(uint2*)&lds_vt[0][vr_d + 32 * i][vc0 + 8] = uint2{vr[i].z, vr[i].w};
    }
    __syncthreads();

    // prologue compute: QK_0 -> pkp_0 (unnormalized exp2)
    bf16x8 pkp[2][2];   // [nt][half], live across iterations
    {
        f32x4 s[4][2] = {};
#pragma unroll
        for (int ks = 0; ks < 4; ++ks) {
            bf16x8 kf[4];
#pragma unroll
            for (int kt = 0; kt < 4; ++kt)
                kf[kt] = *(const bf16x8*)&lds_k[0][kt * 16 + l16][ks * 32 + quad * 8];
#pragma unroll
            for (int kt = 0; kt < 4; ++kt) {
                s[kt][0] = MFMA32(kf[kt], qfrag[0][ks], s[kt][0]);
                s[kt][1] = MFMA32(kf[kt], qfrag[1][ks], s[kt][1]);
            }
        }
#pragma unroll
        for (int nt = 0; nt < 2; ++nt) {
            float ps = 0.f;
            uint_t pb[8];
#pragma unroll
            for (int kt = 0; kt < 4; ++kt) {
                float p0 = exp2_fast(s[kt][nt][0]);
                float p1 = exp2_fast(s[kt][nt][1]);
                float p2 = exp2_fast(s[kt][nt][2]);
                float p3 = exp2_fast(s[kt][nt][3]);
                ps += (p0 + p1) + (p2 + p3);
                __hip_bfloat162 h01 = __float22bfloat162_rn(float2{p0, p1});
                __hip_bfloat162 h23 = __float22bfloat162_rn(float2{p2, p3});
                __builtin_memcpy(&pb[kt * 2 + 0], &h01, 4);
                __builtin_memcpy(&pb[kt * 2 + 1], &h23, 4);
            }
            psum[nt] += ps;
            __builtin_memcpy(&pkp[nt][0], &pb[0], 16);
            __builtin_memcpy(&pkp[nt][1], &pb[4], 16);
        }
    }
    __syncthreads();   // all waves done reading lds_k[0] before iter0 overwrites it

    // main loop: iter it computes PV(tile it) + QK(tile it+1)
    for (int it = 0; it < 63; ++it) {
        int knxt = (it + 1) & 1;   // K_{it+1} read buffer; also V_{it+1} write buffer
        int vcur = it & 1;         // V_it read buffer;    also K_{it+2} write buffer
#pragma unroll
        for (int i = 0; i < 4; ++i) kr[i] = *(const uint4*)(kp + (size_t)i * 16 * CH);
#pragma unroll
        for (int i = 0; i < 4; ++i) vr[i] = *(const uint4*)(vp + (size_t)i * 32 * SEQ);
        kp += 64 * CH; vp += 64;

        // fused MFMA block: QK_{it+1} interleaved with PV_it
        f32x4 s[4][2] = {};
#pragma unroll
        for (int u = 0; u < 4; ++u) {
            bf16x8 kf[4];
#pragma unroll
            for (int kt = 0; kt < 4; ++kt)
                kf[kt] = *(const bf16x8*)&lds_k[knxt][kt * 16 + l16][u * 32 + quad * 8];
#pragma unroll
            for (int kt = 0; kt < 4; ++kt) {
                s[kt][0] = MFMA32(kf[kt], qfrag[0][u], s[kt][0]);
                s[kt][1] = MFMA32(kf[kt], qfrag[1][u], s[kt][1]);
            }
#pragma unroll
            for (int m2 = 0; m2 < 2; ++m2) {
                int mt = u * 2 + m2;
                bf16x8 vf0 = *(const bf16x8*)&lds_vt[vcur][mt * 16 + l16][quad * 8];
                bf16x8 vf1 = *(const bf16x8*)&lds_vt[vcur][mt * 16 + l16][32 + quad * 8];
                oacc[mt][0] = MFMA32(vf0, pkp[0][0], oacc[mt][0]);
                oacc[mt][0] = MFMA32(vf1, pkp[0][1], oacc[mt][0]);
                oacc[mt][1] = MFMA32(vf0, pkp[1][0], oacc[mt][1]);
                oacc[mt][1] = MFMA32(vf1, pkp[1][1], oacc[mt][1]);
            }
        }

        // softmax(tile it+1) -> pkp for next iteration (overlaps store tail)
#pragma unroll
        for (int nt = 0; nt < 2; ++nt) {
            float ps = 0.f;
            uint_t pb[8];
#pragma unroll
            for (int kt = 0; kt < 4; ++kt) {
                float p0 = exp2_fast(s[kt][nt][0]);
                float p1 = exp2_fast(s[kt][nt][1]);
                float p2 = exp2_fast(s[kt][nt][2]);
                float p3 = exp2_fast(s[kt][nt][3]);
                ps += (p0 + p1) + (p2 + p3);
                __hip_bfloat162 h01 = __float22bfloat162_rn(float2{p0, p1});
                __hip_bfloat162 h23 = __float22bfloat162_rn(float2{p2, p3});
                __builtin_memcpy(&pb[kt * 2 + 0], &h01, 4);
                __builtin_memcpy(&pb[kt * 2 + 1], &h23, 4);
            }
            psum[nt] += ps;
            __builtin_memcpy(&pkp[nt][0], &pb[0], 16);
            __builtin_memcpy(&pkp[nt][1], &pb[4], 16);
        }

        // stage writes: K_{it+2} -> lds_k[vcur], V_{it+1} -> lds_vt[knxt]
#pragma unroll
        for (int i = 0; i < 4; ++i) {
            *(uint4*)&lds_k[vcur][kr_row + 16 * i][kr_col] = kr[i];
            *(uint2*)&lds_vt[knxt][vr_d + 32 * i][vc0]     = uint2{vr[i].x, vr[i].y};
            *(uint2*)&lds_vt[knxt][vr_d + 32 * i][vc0 + 8] = uint2{vr[i].z, vr[i].w};
        }
        __syncthreads();   // single barrier per iteration
    }

    // epilogue: PV for tile 63 (lds_vt[1], pkp_63 computed at it=62)
#pragma unroll
    for (int mt = 0; mt < 8; ++mt) {
        bf16x8 vf0 = *(const bf16x8*)&lds_vt[1][mt * 16 + l16][quad * 8];
        bf16x8 vf1 = *(const bf16x8*)&lds_vt[1][mt * 16 + l16][32 + quad * 8];
        oacc[mt][0] = MFMA32(vf0, pkp[0][0], oacc[mt][0]);
        oacc[mt][0] = MFMA32(vf1, pkp[0][1], oacc[mt][0]);
        oacc[mt][1] = MFMA32(vf0, pkp[1][0], oacc[mt][1]);
        oacc[mt][1] = MFMA32(vf1, pkp[1][1], oacc[mt][1]);
    }

    // cross-lane row-sum reduce (once per nt)
    float inv_[2];
#pragma unroll
    for (int nt = 0; nt < 2; ++nt) {
        float tot = psum[nt];
        tot += __shfl_xor(tot, 16, 64);
        tot += __shfl_xor(tot, 32, 64);
        inv_[nt] = 1.f / tot;
    }

    // ---- fused output projection ----
    __syncthreads();   // all waves done reading lds_vt[1]/lds_k before reuse
    // write normalized O rows (bf16) into private per-wave slice of lds_k:
    // slice layout [32 rows][136] (byte stride 272 = 16B-aligned reads).
    // Lane (quad,l16) holds O^T[d=mt*16+quad*4+r][row=nt*16+l16] -> writes
    // 4 consecutive d at [row][mt*16+quad*4] (uint2).
    ushort_t* slice = ((ushort_t*)lds_k) + (size_t)wv * 32 * 136;
#pragma unroll
    for (int nt = 0; nt < 2; ++nt) {
#pragma unroll
        for (int mt = 0; mt < 8; ++mt) {
            ushort_t tmp[4];
#pragma unroll
            for (int r = 0; r < 4; ++r) tmp[r] = f2bf(oacc[mt][nt][r] * inv_[nt]);
            *(uint2*)&slice[(nt * 16 + l16) * 136 + mt * 16 + quad * 4] = *(const uint2*)tmp;
        }
    }
    // O @ Wo + bias + resid -> fp32 out.  A-frags from own slice (same read
    // pattern as gemm_qkv's lds_a); B-frags from L2-resident Wo^T.
#pragma unroll
    for (int nt = 0; nt < 2; ++nt) {
        f32x4 acc2[8] = {};
#pragma unroll
        for (int ks2 = 0; ks2 < 4; ++ks2) {
            bf16x8 afrag = *(const bf16x8*)&slice[(nt * 16 + l16) * 136 + ks2 * 32 + quad * 8];
#pragma unroll
            for (int tc = 0; tc < 8; ++tc) {
                bf16x8 bfrag = *(const bf16x8*)(wto + (size_t)(tc * 16 + l16) * CH + ks2 * 32 + quad * 8);
                acc2[tc] = MFMA32(afrag, bfrag, acc2[tc]);
            }
        }
        size_t rowbase = (size_t)b * SEQ + qrow_base + nt * 16 + quad * 4;
#pragma unroll
        for (int tc = 0; tc < 8; ++tc) {
            int col = tc * 16 + l16;
            float bval = Bo[col];
#pragma unroll
            for (int r = 0; r < 4; ++r) {
                size_t row = rowbase + r;
                outp[row * CH + col] = acc2[tc][r] + bval + xres[row * CH + col];
            }
        }
    }
}

extern "C" void kernel_launch(void* const* d_in, const int* in_sizes, int n_in,
                              void* d_out, int out_size, void* d_ws, size_t ws_size,
                              hipStream_t stream) {
    const float* x   = (const float*)d_in[0];
    const float* gsc = (const float*)d_in[1];
    const float* gbi = (const float*)d_in[2];
    const float* wq  = (const float*)d_in[3];
    const float* bq  = (const float*)d_in[4];
    const float* wk  = (const float*)d_in[5];
    const float* bk  = (const float*)d_in[6];
    const float* wvp = (const float*)d_in[7];
    const float* bv  = (const float*)d_in[8];
    const float* wo  = (const float*)d_in[9];
    const float* bo  = (const float*)d_in[10];
    float* outp = (float*)d_out;

    const size_t NELEM = (size_t)BATCH * SEQ * CH;  // 8388608
    ushort_t* qbuf  = (ushort_t*)d_ws;
    ushort_t* kbuf  = qbuf + NELEM;
    ushort_t* vtbuf = kbuf + NELEM;
    ushort_t* wtbuf = vtbuf + NELEM;   // 4 x 128x128 bf16 W^T (128 KB)
    float*    stats = (float*)(wtbuf + 4 * CH * CH);  // 16x16x32x2 raw sums (64 KB)
    // note: flash_attn21 prefetches one K tile past the K buffer end (reads
    // land in vtbuf) and ~256B past vtbuf (lands in wtbuf); values unused —
    // keep buffer order qbuf,kbuf,vtbuf,wtbuf,stats.

    gn_wprep<<<260, 256, 0, stream>>>(x, stats, wq, wk, wvp, wo, wtbuf);
    gemm_qkv<<<512, 256, 0, stream>>>(x, stats, gsc, gbi, wtbuf, bq, bk, bv,
                                      qbuf, kbuf, vtbuf);
    flash_attn21<<<512, 256, 0, stream>>>(qbuf, kbuf, vtbuf,
                                          wtbuf + 3 * CH * CH, bo, x, outp);
}

// Round 11
// 266.648 us; speedup vs baseline: 1.1354x; 1.0443x over previous
//
#include <hip/hip_runtime.h>
#include <hip/hip_bf16.h>

typedef unsigned short ushort_t;
typedef unsigned int uint_t;
typedef __attribute__((ext_vector_type(8))) short bf16x8;
typedef __attribute__((ext_vector_type(4))) float f32x4;

#define MFMA32(a, b, c) __builtin_amdgcn_mfma_f32_16x16x32_bf16(a, b, c, 0, 0, 0)

static constexpr int BATCH = 16;
static constexpr int SEQ   = 4096;   // H*W
static constexpr int CH    = 128;
static constexpr int NGRP  = 32;
static constexpr float EPS = 1e-6f;
// softmax scale folded into exp2 domain AND pre-folded into Q projection:
static constexpr float C2 = 0.08838834764831845f * 1.4426950408889634f;

__device__ inline ushort_t f2bf(float f) {
    uint_t u = __float_as_uint(f);
    u = (u + 0x7fff + ((u >> 16) & 1)) >> 16;
    return (ushort_t)u;
}

// bare v_exp_f32 via the clang intrinsic (schedulable, promotable — no inline
// asm).  Args bounded |x|<~35 in this kernel -> in-range, matches exp2f.
// (r16/r17/r18 A-B: inline-asm variants and s_setprio both induce ~17MB of
// scheduling spill traffic; this intrinsic alone is clean: 168.8->139.6us.)
__device__ inline float exp2_fast(float x) {
    return __builtin_amdgcn_exp2f(x);
}

// ---------------- fused GN-partial + weight prep (one launch) ----------------
// blocks 0..255: GroupNorm partial sums, NON-ATOMIC into private per-chunk
// slots stats[b][chunk][g][2]; gemm_qkv finalizes by summing the 16 slots.
// blocks 256..259: W fp32 [k][n] -> Wt bf16 [n][k] (L2-resident afterwards).
__global__ __launch_bounds__(256) void gn_wprep(const float* __restrict__ x,
                                                float* __restrict__ stats,
                                                const float* __restrict__ W0,
                                                const float* __restrict__ W1,
                                                const float* __restrict__ W2,
                                                const float* __restrict__ W3,
                                                ushort_t* __restrict__ wt) {
    int bid = blockIdx.x;
    int t = threadIdx.x;
    if (bid >= 256) {
        // ---- weight prep ----
        int m = bid - 256;
        const float* Ws[4] = {W0, W1, W2, W3};
        const float* W = Ws[m];
        ushort_t* out = wt + (size_t)m * CH * CH;
        __shared__ ushort_t tile[128][130];
        for (int i = 0; i < 16; ++i) {
            int idx = (t + i * 256) * 4;
            int kk = idx >> 7, n = idx & 127;
            float4 w4 = *(const float4*)(W + (size_t)kk * CH + n);
            tile[n + 0][kk] = f2bf(w4.x);
            tile[n + 1][kk] = f2bf(w4.y);
            tile[n + 2][kk] = f2bf(w4.z);
            tile[n + 3][kk] = f2bf(w4.w);
        }
        __syncthreads();
        for (int i = 0; i < 8; ++i) {
            int idx = (t + i * 256) * 8;
            int n = idx >> 7, kk = idx & 127;
            ushort_t tmp[8];
            for (int u = 0; u < 8; ++u) tmp[u] = tile[n][kk + u];
            *(uint4*)&out[(size_t)n * CH + kk] = *(const uint4*)tmp;
        }
        return;
    }
    // ---- GN partial sums ----
    int b = bid >> 4, chunk = bid & 15;
    int c4 = (t & 31) * 4;   // one group = 4 channels
    int rowoff = t >> 5;     // 0..7
    const float* xb = x + (size_t)b * SEQ * CH;
    float s1 = 0.f, s2 = 0.f;
    int base_row = chunk * 256;
    for (int i = 0; i < 32; ++i) {
        int r = base_row + i * 8 + rowoff;
        float4 v = *(const float4*)(xb + (size_t)r * CH + c4);
        s1 += v.x + v.y + v.z + v.w;
        s2 += v.x * v.x + v.y * v.y + v.z * v.z + v.w * v.w;
    }
    __shared__ float red[256][2];
    red[t][0] = s1; red[t][1] = s2;
    __syncthreads();
    if (t < 32) {
        float a1 = 0.f, a2 = 0.f;
        for (int ro = 0; ro < 8; ++ro) {
            a1 += red[ro * 32 + t][0];
            a2 += red[ro * 32 + t][1];
        }
        float* slot = stats + ((size_t)(b * 16 + chunk) * 32 + t) * 2;
        slot[0] = a1;
        slot[1] = a2;
    }
}

// ---------------- fused normalize + QKV GEMM (r22) ---------------------------
// r21 analysis: gemm_qkv ~95-100us vs ~20us floor.  Two fixes:
// (1) B-fragments: stage each projection's Wt (bf16, plain uint4 copy — no
//     f2bf) into lds_w once per block; MFMA reads become shared low-latency
//     LDS reads instead of 96KB/wave of dependent ~200cyc L2 loads.
// (2) V^T epilogue: was 8B-per-lane scatter at col*SEQ stride (~2M 8B L2
//     write transactions).  Now: C-fragments -> transpose in dead lds_a ->
//     coalesced copy-out (lane pairs cover 256B contiguous seq).  Bit-
//     identical values, ~16x fewer write transactions.
__global__ __launch_bounds__(256) void gemm_qkv(const float* __restrict__ x,
                                                const float* __restrict__ stats,
                                                const float* __restrict__ gsc,
                                                const float* __restrict__ gbi,
                                                const ushort_t* __restrict__ wt,
                                                const float* __restrict__ Bq,
                                                const float* __restrict__ Bk,
                                                const float* __restrict__ Bv,
                                                ushort_t* __restrict__ outq,
                                                ushort_t* __restrict__ outk,
                                                ushort_t* __restrict__ outvt) {
    __shared__ ushort_t lds_a[128][136];  // normalized A tile; reused as V^T transpose buf
    __shared__ ushort_t lds_w[128][136];  // current projection's Wt[n][k]
    __shared__ float2 gstat[32];
    int t = threadIdx.x;
    int wv = t >> 6, lane = t & 63, quad = lane >> 4, l16 = lane & 15;
    size_t m0 = (size_t)blockIdx.x * 128;
    int batch = (int)(m0 >> 12);
    int seq0  = (int)(m0 & 4095);
    // gn_finalize: sum the 16 per-chunk raw slots for this batch
    if (t < 32) {
        float sum = 0.f, sq = 0.f;
        for (int c = 0; c < 16; ++c) {
            const float* slot = stats + ((size_t)(batch * 16 + c) * 32 + t) * 2;
            sum += slot[0];
            sq  += slot[1];
        }
        float mean = sum / 16384.f;
        float var  = sq / 16384.f - mean * mean;
        gstat[t] = float2{mean, __frsqrt_rn(var + EPS)};
    }
    __syncthreads();
    // stage A (normalize x -> h in flight) and W0 concurrently
    for (int i = 0; i < 8; ++i) {
        int idx = (t + i * 256) * 8;
        int r = idx >> 7, c = idx & 127;
        size_t row = m0 + r;
        float4 xa = *(const float4*)(x + row * CH + c);
        float4 xc = *(const float4*)(x + row * CH + c + 4);
        float2 stA = gstat[c >> 2];
        float2 stB = gstat[(c >> 2) + 1];
        float4 sA = *(const float4*)(gsc + c), sB = *(const float4*)(gsc + c + 4);
        float4 bA = *(const float4*)(gbi + c), bB = *(const float4*)(gbi + c + 4);
        ushort_t tmp[8];
        tmp[0] = f2bf((xa.x - stA.x) * stA.y * sA.x + bA.x);
        tmp[1] = f2bf((xa.y - stA.x) * stA.y * sA.y + bA.y);
        tmp[2] = f2bf((xa.z - stA.x) * stA.y * sA.z + bA.z);
        tmp[3] = f2bf((xa.w - stA.x) * stA.y * sA.w + bA.w);
        tmp[4] = f2bf((xc.x - stB.x) * stB.y * sB.x + bB.x);
        tmp[5] = f2bf((xc.y - stB.x) * stB.y * sB.y + bB.y);
        tmp[6] = f2bf((xc.z - stB.x) * stB.y * sB.z + bB.z);
        tmp[7] = f2bf((xc.w - stB.x) * stB.y * sB.w + bB.w);
        *(uint4*)&lds_a[r][c] = *(const uint4*)tmp;
    }
    for (int i = 0; i < 8; ++i) {
        int idx = (t + i * 256) * 8;
        int n = idx >> 7, kk = idx & 127;
        *(uint4*)&lds_w[n][kk] = *(const uint4*)(wt + (size_t)n * CH + kk);
    }
    __syncthreads();   // A and W0 ready
    for (int j = 0; j < 3; ++j) {
        const float* Bi = (j == 0) ? Bq : (j == 1) ? Bk : Bv;
        f32x4 acc[2][8] = {};
        for (int kh = 0; kh < 2; ++kh) {
            int k0 = kh * 64;
            for (int ks = 0; ks < 2; ++ks) {
                bf16x8 afrag[2];
                for (int tr = 0; tr < 2; ++tr)
                    afrag[tr] = *(const bf16x8*)&lds_a[wv * 32 + tr * 16 + l16][k0 + ks * 32 + quad * 8];
                for (int tc = 0; tc < 8; ++tc) {
                    bf16x8 bfrag = *(const bf16x8*)&lds_w[tc * 16 + l16][k0 + ks * 32 + quad * 8];
                    for (int tr = 0; tr < 2; ++tr)
                        acc[tr][tc] = MFMA32(afrag[tr], bfrag, acc[tr][tc]);
                }
            }
        }
        if (j < 2) {
            // direct epilogue for q/k, then restage lds_w for j+1
            for (int tc = 0; tc < 8; ++tc) {
                int col = tc * 16 + l16;
                float bval = Bi[col];
                ushort_t* op = (j == 0) ? outq : outk;
                for (int tr = 0; tr < 2; ++tr) {
                    int rl = wv * 32 + tr * 16 + quad * 4;
                    for (int r = 0; r < 4; ++r) {
                        float vv = acc[tr][tc][r] + bval;
                        if (j == 0) vv *= C2;   // fold softmax scale into q
                        op[(m0 + rl + r) * CH + col] = f2bf(vv);
                    }
                }
            }
            __syncthreads();   // all waves done reading lds_w[j]
            const ushort_t* wtn = wt + (size_t)(j + 1) * CH * CH;
            for (int i = 0; i < 8; ++i) {
                int idx = (t + i * 256) * 8;
                int n = idx >> 7, kk = idx & 127;
                *(uint4*)&lds_w[n][kk] = *(const uint4*)(wtn + (size_t)n * CH + kk);
            }
            __syncthreads();   // W_{j+1} ready
        } else {
            // V^T epilogue via LDS transpose (lds_a is dead after j=2's afrag reads)
            __syncthreads();   // all waves done reading lds_a
            for (int tc = 0; tc < 8; ++tc) {
                int col = tc * 16 + l16;
                float bval = Bi[col];
                for (int tr = 0; tr < 2; ++tr) {
                    int sl = wv * 32 + tr * 16 + quad * 4;
                    ushort_t tmp[4];
                    for (int r = 0; r < 4; ++r) tmp[r] = f2bf(acc[tr][tc][r] + bval);
                    *(uint2*)&lds_a[col][sl] = *(const uint2*)tmp;   // [col][seq_local]
                }
            }
            __syncthreads();
            // coalesced copy-out: thread t covers 64 seq of one column
            int col = t >> 1, s0 = (t & 1) * 64;
            ushort_t* dst = outvt + (size_t)batch * CH * SEQ + (size_t)col * SEQ + seq0 + s0;
            for (int u = 0; u < 8; ++u)
                *(uint4*)&dst[u * 8] = *(const uint4*)&lds_a[col][s0 + u * 8];
        }
    }
}

// ---------------- flash attention r21 (UNCHANGED — 162.4us verified) ---------
// r18 core (cross-iteration pipeline, unnormalized exp2 softmax, dbuf,
// 1 barrier/iter, no setprio) + fused output projection in dead lds_k.
__global__ __launch_bounds__(256, 2) void flash_attn21(const ushort_t* __restrict__ q,
                                                       const ushort_t* __restrict__ k,
                                                       const ushort_t* __restrict__ vt,
                                                       const ushort_t* __restrict__ wto,
                                                       const float* __restrict__ Bo,
                                                       const float* __restrict__ xres,
                                                       float* __restrict__ outp) {
    int bid = blockIdx.x;
    int b = bid & 15, qt = bid >> 4;
    int t = threadIdx.x;
    int wv = t >> 6, lane = t & 63, quad = lane >> 4, l16 = lane & 15;
    const size_t SB = (size_t)SEQ * CH;
    const ushort_t* qb  = q  + (size_t)b * SB;
    const ushort_t* kb  = k  + (size_t)b * SB;
    const ushort_t* vtb = vt + (size_t)b * SB;   // [d][seq]

    __shared__ ushort_t lds_k[2][64][136];    // [buf][key][d]; reused as O slices
    __shared__ ushort_t lds_vt[2][128][72];   // [buf][d][key_local PERMUTED]

    int qrow_base = qt * 128 + wv * 32;       // 4 waves x 32 q-rows
    bf16x8 qfrag[2][4];
#pragma unroll
    for (int nt = 0; nt < 2; ++nt)
#pragma unroll
        for (int ks = 0; ks < 4; ++ks)
            qfrag[nt][ks] = *(const bf16x8*)(qb + (size_t)(qrow_base + nt * 16 + l16) * CH + ks * 32 + quad * 8);

    f32x4 oacc[8][2] = {};        // [mt=d/16][nt]
    float psum[2] = {0.f, 0.f};   // per-lane partial row-sums (reduced at end)

    int kr_row  = t >> 4;          // 0..15 (+16i)
    int kr_col  = (t & 15) * 8;
    int vr_d    = t >> 3;          // 0..31 (+32i)
    int vr_beta = t & 7;
    int vc0 = 32 * (vr_beta >> 2) + 16 * (vr_beta & 1) + 4 * ((vr_beta >> 1) & 1);

    const ushort_t* kp = kb + (size_t)kr_row * CH + kr_col;
    const ushort_t* vp = vtb + (size_t)vr_d * SEQ + vr_beta * 8;

    uint4 kr[4], vr[4], k1[4];
#pragma unroll
    for (int i = 0; i < 4; ++i) kr[i] = *(const uint4*)(kp + (size_t)i * 16 * CH);
#pragma unroll
    for (int i = 0; i < 4; ++i) vr[i] = *(const uint4*)(vp + (size_t)i * 32 * SEQ);
#pragma unroll
    for (int i = 0; i < 4; ++i) k1[i] = *(const uint4*)(kp + (size_t)(64 + i * 16) * CH);
    kp += 2 * 64 * CH;   // -> tile 2
    vp += 64;            // -> tile 1
#pragma unroll
    for (int i = 0; i < 4; ++i) {
        *(uint4*)&lds_k[0][kr_row + 16 * i][kr_col] = kr[i];
        *(uint4*)&lds_k[1][kr_row + 16 * i][kr_col] = k1[i];
        *(uint2*)&lds_vt[0][vr_d + 32 * i][vc0]     = uint2{vr[i].x, vr[i].y};
        *(uint2*)&lds_vt[0][vr_d + 32 * i][vc0 + 8] = uint2{vr[i].z, vr[i].w};
    }
    __syncthreads();

    // prologue compute: QK_0 -> pkp_0 (unnormalized exp2)
    bf16x8 pkp[2][2];   // [nt][half], live across iterations
    {
        f32x4 s[4][2] = {};
#pragma unroll
        for (int ks = 0; ks < 4; ++ks) {
            bf16x8 kf[4];
#pragma unroll
            for (int kt = 0; kt < 4; ++kt)
                kf[kt] = *(const bf16x8*)&lds_k[0][kt * 16 + l16][ks * 32 + quad * 8];
#pragma unroll
            for (int kt = 0; kt < 4; ++kt) {
                s[kt][0] = MFMA32(kf[kt], qfrag[0][ks], s[kt][0]);
                s[kt][1] = MFMA32(kf[kt], qfrag[1][ks], s[kt][1]);
            }
        }
#pragma unroll
        for (int nt = 0; nt < 2; ++nt) {
            float ps = 0.f;
            uint_t pb[8];
#pragma unroll
            for (int kt = 0; kt < 4; ++kt) {
                float p0 = exp2_fast(s[kt][nt][0]);
                float p1 = exp2_fast(s[kt][nt][1]);
                float p2 = exp2_fast(s[kt][nt][2]);
                float p3 = exp2_fast(s[kt][nt][3]);
                ps += (p0 + p1) + (p2 + p3);
                __hip_bfloat162 h01 = __float22bfloat162_rn(float2{p0, p1});
                __hip_bfloat162 h23 = __float22bfloat162_rn(float2{p2, p3});
                __builtin_memcpy(&pb[kt * 2 + 0], &h01, 4);
                __builtin_memcpy(&pb[kt * 2 + 1], &h23, 4);
            }
            psum[nt] += ps;
            __builtin_memcpy(&pkp[nt][0], &pb[0], 16);
            __builtin_memcpy(&pkp[nt][1], &pb[4], 16);
        }
    }
    __syncthreads();   // all waves done reading lds_k[0] before iter0 overwrites it

    // main loop: iter it computes PV(tile it) + QK(tile it+1)
    for (int it = 0; it < 63; ++it) {
        int knxt = (it + 1) & 1;   // K_{it+1} read buffer; also V_{it+1} write buffer
        int vcur = it & 1;         // V_it read buffer;    also K_{it+2} write buffer
#pragma unroll
        for (int i = 0; i < 4; ++i) kr[i] = *(const uint4*)(kp + (size_t)i * 16 * CH);
#pragma unroll
        for (int i = 0; i < 4; ++i) vr[i] = *(const uint4*)(vp + (size_t)i * 32 * SEQ);
        kp += 64 * CH; vp += 64;

        // fused MFMA block: QK_{it+1} interleaved with PV_it
        f32x4 s[4][2] = {};
#pragma unroll
        for (int u = 0; u < 4; ++u) {
            bf16x8 kf[4];
#pragma unroll
            for (int kt = 0; kt < 4; ++kt)
                kf[kt] = *(const bf16x8*)&lds_k[knxt][kt * 16 + l16][u * 32 + quad * 8];
#pragma unroll
            for (int kt = 0; kt < 4; ++kt) {
                s[kt][0] = MFMA32(kf[kt], qfrag[0][u], s[kt][0]);
                s[kt][1] = MFMA32(kf[kt], qfrag[1][u], s[kt][1]);
            }
#pragma unroll
            for (int m2 = 0; m2 < 2; ++m2) {
                int mt = u * 2 + m2;
                bf16x8 vf0 = *(const bf16x8*)&lds_vt[vcur][mt * 16 + l16][quad * 8];
                bf16x8 vf1 = *(const bf16x8*)&lds_vt[vcur][mt * 16 + l16][32 + quad * 8];
                oacc[mt][0] = MFMA32(vf0, pkp[0][0], oacc[mt][0]);
                oacc[mt][0] = MFMA32(vf1, pkp[0][1], oacc[mt][0]);
                oacc[mt][1] = MFMA32(vf0, pkp[1][0], oacc[mt][1]);
                oacc[mt][1] = MFMA32(vf1, pkp[1][1], oacc[mt][1]);
            }
        }

        // softmax(tile it+1) -> pkp for next iteration (overlaps store tail)
#pragma unroll
        for (int nt = 0; nt < 2; ++nt) {
            float ps = 0.f;
            uint_t pb[8];
#pragma unroll
            for (int kt = 0; kt < 4; ++kt) {
                float p0 = exp2_fast(s[kt][nt][0]);
                float p1 = exp2_fast(s[kt][nt][1]);
                float p2 = exp2_fast(s[kt][nt][2]);
                float p3 = exp2_fast(s[kt][nt][3]);
                ps += (p0 + p1) + (p2 + p3);
                __hip_bfloat162 h01 = __float22bfloat162_rn(float2{p0, p1});
                __hip_bfloat162 h23 = __float22bfloat162_rn(float2{p2, p3});
                __builtin_memcpy(&pb[kt * 2 + 0], &h01, 4);
                __builtin_memcpy(&pb[kt * 2 + 1], &h23, 4);
            }
            psum[nt] += ps;
            __builtin_memcpy(&pkp[nt][0], &pb[0], 16);
            __builtin_memcpy(&pkp[nt][1], &pb[4], 16);
        }

        // stage writes: K_{it+2} -> lds_k[vcur], V_{it+1} -> lds_vt[knxt]
#pragma unroll
        for (int i = 0; i < 4; ++i) {
            *(uint4*)&lds_k[vcur][kr_row + 16 * i][kr_col] = kr[i];
            *(uint2*)&lds_vt[knxt][vr_d + 32 * i][vc0]     = uint2{vr[i].x, vr[i].y};
            *(uint2*)&lds_vt[knxt][vr_d + 32 * i][vc0 + 8] = uint2{vr[i].z, vr[i].w};
        }
        __syncthreads();   // single barrier per iteration
    }

    // epilogue: PV for tile 63 (lds_vt[1], pkp_63 computed at it=62)
#pragma unroll
    for (int mt = 0; mt < 8; ++mt) {
        bf16x8 vf0 = *(const bf16x8*)&lds_vt[1][mt * 16 + l16][quad * 8];
        bf16x8 vf1 = *(const bf16x8*)&lds_vt[1][mt * 16 + l16][32 + quad * 8];
        oacc[mt][0] = MFMA32(vf0, pkp[0][0], oacc[mt][0]);
        oacc[mt][0] = MFMA32(vf1, pkp[0][1], oacc[mt][0]);
        oacc[mt][1] = MFMA32(vf0, pkp[1][0], oacc[mt][1]);
        oacc[mt][1] = MFMA32(vf1, pkp[1][1], oacc[mt][1]);
    }

    // cross-lane row-sum reduce (once per nt)
    float inv_[2];
#pragma unroll
    for (int nt = 0; nt < 2; ++nt) {
        float tot = psum[nt];
        tot += __shfl_xor(tot, 16, 64);
        tot += __shfl_xor(tot, 32, 64);
        inv_[nt] = 1.f / tot;
    }

    // ---- fused output projection ----
    __syncthreads();   // all waves done reading lds_vt[1]/lds_k before reuse
    ushort_t* slice = ((ushort_t*)lds_k) + (size_t)wv * 32 * 136;
#pragma unroll
    for (int nt = 0; nt < 2; ++nt) {
#pragma unroll
        for (int mt = 0; mt < 8; ++mt) {
            ushort_t tmp[4];
#pragma unroll
            for (int r = 0; r < 4; ++r) tmp[r] = f2bf(oacc[mt][nt][r] * inv_[nt]);
            *(uint2*)&slice[(nt * 16 + l16) * 136 + mt * 16 + quad * 4] = *(const uint2*)tmp;
        }
    }
#pragma unroll
    for (int nt = 0; nt < 2; ++nt) {
        f32x4 acc2[8] = {};
#pragma unroll
        for (int ks2 = 0; ks2 < 4; ++ks2) {
            bf16x8 afrag = *(const bf16x8*)&slice[(nt * 16 + l16) * 136 + ks2 * 32 + quad * 8];
#pragma unroll
            for (int tc = 0; tc < 8; ++tc) {
                bf16x8 bfrag = *(const bf16x8*)(wto + (size_t)(tc * 16 + l16) * CH + ks2 * 32 + quad * 8);
                acc2[tc] = MFMA32(afrag, bfrag, acc2[tc]);
            }
        }
        size_t rowbase = (size_t)b * SEQ + qrow_base + nt * 16 + quad * 4;
#pragma unroll
        for (int tc = 0; tc < 8; ++tc) {
            int col = tc * 16 + l16;
            float bval = Bo[col];
#pragma unroll
            for (int r = 0; r < 4; ++r) {
                size_t row = rowbase + r;
                outp[row * CH + col] = acc2[tc][r] + bval + xres[row * CH + col];
            }
        }
    }
}

extern "C" void kernel_launch(void* const* d_in, const int* in_sizes, int n_in,
                              void* d_out, int out_size, void* d_ws, size_t ws_size,
                              hipStream_t stream) {
    const float* x   = (const float*)d_in[0];
    const float* gsc = (const float*)d_in[1];
    const float* gbi = (const float*)d_in[2];
    const float* wq  = (const float*)d_in[3];
    const float* bq  = (const float*)d_in[4];
    const float* wk  = (const float*)d_in[5];
    const float* bk  = (const float*)d_in[6];
    const float* wvp = (const float*)d_in[7];
    const float* bv  = (const float*)d_in[8];
    const float* wo  = (const float*)d_in[9];
    const float* bo  = (const float*)d_in[10];
    float* outp = (float*)d_out;

    const size_t NELEM = (size_t)BATCH * SEQ * CH;  // 8388608
    ushort_t* qbuf  = (ushort_t*)d_ws;
    ushort_t* kbuf  = qbuf + NELEM;
    ushort_t* vtbuf = kbuf + NELEM;
    ushort_t* wtbuf = vtbuf + NELEM;   // 4 x 128x128 bf16 W^T (128 KB)
    float*    stats = (float*)(wtbuf + 4 * CH * CH);  // 16x16x32x2 raw sums (64 KB)
    // note: flash_attn21 prefetches one K tile past the K buffer end (reads
    // land in vtbuf) and ~256B past vtbuf (lands in wtbuf); values unused —
    // keep buffer order qbuf,kbuf,vtbuf,wtbuf,stats.

    gn_wprep<<<260, 256, 0, stream>>>(x, stats, wq, wk, wvp, wo, wtbuf);
    gemm_qkv<<<512, 256, 0, stream>>>(x, stats, gsc, gbi, wtbuf, bq, bk, bv,
                                      qbuf, kbuf, vtbuf);
    flash_attn21<<<512, 256, 0, stream>>>(qbuf, kbuf, vtbuf,
                                          wtbuf + 3 * CH * CH, bo, x, outp);
}